// Round 1
// baseline (1375.603 us; speedup 1.0000x reference)
//
#include <hip/hip_runtime.h>

using half8  = __attribute__((ext_vector_type(8))) _Float16;
using half4v = __attribute__((ext_vector_type(4))) _Float16;
using f32x4  = __attribute__((ext_vector_type(4))) float;

#define H_DIM 4096
#define NTOK  8192

// ---------------------------------------------------------------------------
// async global -> LDS, 16 bytes per lane. LDS dest is WAVE-UNIFORM base;
// hardware writes at base + lane*16. Global address is per-lane.
// ---------------------------------------------------------------------------
__device__ __forceinline__ void gld_lds16(void* lds, const void* g) {
  __builtin_amdgcn_global_load_lds((const __attribute__((address_space(1))) void*)g,
                                   (__attribute__((address_space(3))) void*)lds,
                                   16, 0, 0);
}

// ---------------------------------------------------------------------------
// Pack one fp32 weight [K][N] into f16 packed layout [K/8][N][8]:
//   packed[(k/8)*N*8 + n*8 + (k%8)] = (f16) w[k*N + n]
// Reads coalesced per k-row; writes 16B contiguous per thread.
// grid = (K/8, N/256), block = 256
// ---------------------------------------------------------------------------
__global__ void pack_w_kernel(const float* __restrict__ w, _Float16* __restrict__ bp) {
  const int kg = blockIdx.x;                       // 0..511
  const int n  = blockIdx.y * 256 + threadIdx.x;   // 0..4095
  half8 h;
#pragma unroll
  for (int j = 0; j < 8; ++j) {
    h[j] = (_Float16)w[(size_t)(kg * 8 + j) * H_DIM + n];
  }
  *(half8*)(bp + ((size_t)kg * H_DIM + n) * 8) = h;
}

// ---------------------------------------------------------------------------
// Row RMSNorm, one block (256 threads) per row, 16 f32/thread in registers.
// MODE 0: in = x (fp32): z = relu(in); resid_out = z; y16 = rmsnorm(z)*g
// MODE 1: in = resid:                     y16 = rmsnorm(in)*g
// MODE 2: in = resid:    y32 (in-place ok) = rmsnorm(in)*g   (final output)
// ---------------------------------------------------------------------------
template <int MODE>
__global__ void rownorm_kernel(const float* in, const float* __restrict__ g,
                               float* resid_out, _Float16* y16, float* y32) {
  const int row = blockIdx.x;
  const int tid = threadIdx.x;
  const float* rp = in + (size_t)row * H_DIM;

  float4 v[4];
  float ss = 0.f;
#pragma unroll
  for (int p = 0; p < 4; ++p) {
    v[p] = *(const float4*)(rp + p * 1024 + tid * 4);
    if (MODE == 0) {
      v[p].x = fmaxf(v[p].x, 0.f);
      v[p].y = fmaxf(v[p].y, 0.f);
      v[p].z = fmaxf(v[p].z, 0.f);
      v[p].w = fmaxf(v[p].w, 0.f);
    }
    ss += v[p].x * v[p].x + v[p].y * v[p].y + v[p].z * v[p].z + v[p].w * v[p].w;
  }
  // wave64 reduce
#pragma unroll
  for (int o = 32; o > 0; o >>= 1) ss += __shfl_xor(ss, o, 64);
  __shared__ float sred[4];
  if ((tid & 63) == 0) sred[tid >> 6] = ss;
  __syncthreads();
  ss = sred[0] + sred[1] + sred[2] + sred[3];
  const float scale = rsqrtf(ss * (1.0f / (float)H_DIM) + 1e-6f);

  if (MODE == 0) {
#pragma unroll
    for (int p = 0; p < 4; ++p)
      *(float4*)(resid_out + (size_t)row * H_DIM + p * 1024 + tid * 4) = v[p];
  }
#pragma unroll
  for (int p = 0; p < 4; ++p) {
    float4 gv = *(const float4*)(g + p * 1024 + tid * 4);
    float4 yv;
    yv.x = v[p].x * scale * gv.x;
    yv.y = v[p].y * scale * gv.y;
    yv.z = v[p].z * scale * gv.z;
    yv.w = v[p].w * scale * gv.w;
    if (MODE == 2) {
      *(float4*)(y32 + (size_t)row * H_DIM + p * 1024 + tid * 4) = yv;
    } else {
      half4v h;
      h[0] = (_Float16)yv.x; h[1] = (_Float16)yv.y;
      h[2] = (_Float16)yv.z; h[3] = (_Float16)yv.w;
      *(half4v*)(y16 + (size_t)row * H_DIM + p * 1024 + tid * 4) = h;
    }
  }
}

// ---------------------------------------------------------------------------
// GEMM: resid[M][N] += A_f16[M][K] * Bpacked_f16[K/8][N][8]
// 128x128 tile, BK=32, 4 waves (2x2), 16x16x32 f16 MFMA, m97 structure:
// global_load_lds(16B) staging, 2-barrier K-loop.
// LDS A: [m][ko] row-major 64B rows, chunk XOR-swizzled by (m&3) on BOTH the
//        global source and the ds_read address (bank-conflict fix, rule 21).
// LDS B: [ko][n][8k] (pre-packed global layout => linear, conflict-free).
// ---------------------------------------------------------------------------
__global__ __launch_bounds__(256, 2) void gemm128_kernel(
    const _Float16* __restrict__ A, const _Float16* __restrict__ Bp,
    float* __restrict__ C) {
  __shared__ _Float16 sA[128 * 32];      // 8 KB
  __shared__ _Float16 sB[4 * 128 * 8];   // 8 KB

  const int tid  = threadIdx.x;
  const int lane = tid & 63;
  const int wid  = tid >> 6;   // 0..3
  const int wr   = wid >> 1;   // 0..1
  const int wc   = wid & 1;    // 0..1
  const int bm   = blockIdx.y * 128;
  const int bn   = blockIdx.x * 128;

  // --- staging pointers (2 rounds each for A and B; 512 chunks of 16B) ---
  const _Float16* gA[2];
  const _Float16* gB[2];
  _Float16* lA[2];
  _Float16* lB[2];
#pragma unroll
  for (int r = 0; r < 2; ++r) {
    const int c = r * 256 + tid;
    // A: m = c>>2, ko_lds = c&3, global ko = ko_lds ^ (m&3)  (self-inverse)
    const int m   = c >> 2;
    const int kog = (c & 3) ^ (m & 3);
    gA[r] = A + (size_t)(bm + m) * H_DIM + kog * 8;
    lA[r] = sA + (size_t)(r * 256 + wid * 64) * 8;   // wave-uniform base
    // B: ko = c>>7, n = c&127; packed global chunk = (kt*4+ko)*N + bn + n
    const int ko = c >> 7;
    const int n  = c & 127;
    gB[r] = Bp + ((size_t)ko * H_DIM + bn + n) * 8;
    lB[r] = sB + (size_t)(r * 256 + wid * 64) * 8;
  }

  // --- ds_read byte offsets (fixed per thread) ---
  int aoff[4], boff[4];
#pragma unroll
  for (int mi = 0; mi < 4; ++mi) {
    const int ml = wr * 64 + mi * 16 + (lane & 15);
    const int ko = lane >> 4;
    aoff[mi] = ml * 64 + ((ko ^ (ml & 3)) << 4);
  }
#pragma unroll
  for (int ni = 0; ni < 4; ++ni) {
    const int nl = wc * 64 + ni * 16 + (lane & 15);
    boff[ni] = (lane >> 4) * 2048 + nl * 16;
  }

  f32x4 acc[4][4];
#pragma unroll
  for (int mi = 0; mi < 4; ++mi)
#pragma unroll
    for (int ni = 0; ni < 4; ++ni) acc[mi][ni] = (f32x4)0.f;

  const char* sAc = (const char*)sA;
  const char* sBc = (const char*)sB;

  for (int kt = 0; kt < H_DIM / 32; ++kt) {
    // stage tile kt (async 16B per lane)
#pragma unroll
    for (int r = 0; r < 2; ++r) {
      gld_lds16(lA[r], gA[r]);
      gld_lds16(lB[r], gB[r]);
      gA[r] += 32;                       // next K-step: +32 halfs
      gB[r] += (size_t)4 * H_DIM * 8;    // next 4 k-groups
    }
    __syncthreads();  // compiler drains vmcnt before barrier

    half8 af[4], bf[4];
#pragma unroll
    for (int mi = 0; mi < 4; ++mi) af[mi] = *(const half8*)(sAc + aoff[mi]);
#pragma unroll
    for (int ni = 0; ni < 4; ++ni) bf[ni] = *(const half8*)(sBc + boff[ni]);

#pragma unroll
    for (int mi = 0; mi < 4; ++mi)
#pragma unroll
      for (int ni = 0; ni < 4; ++ni)
        acc[mi][ni] = __builtin_amdgcn_mfma_f32_16x16x32_f16(af[mi], bf[ni],
                                                             acc[mi][ni], 0, 0, 0);
    __syncthreads();  // protect LDS before next stage overwrites
  }

  // epilogue: resid += C.  C/D layout: col = lane&15, row = (lane>>4)*4 + reg
#pragma unroll
  for (int mi = 0; mi < 4; ++mi) {
    const int row0 = bm + wr * 64 + mi * 16 + (lane >> 4) * 4;
#pragma unroll
    for (int ni = 0; ni < 4; ++ni) {
      const int col = bn + wc * 64 + ni * 16 + (lane & 15);
      float* p = C + (size_t)row0 * H_DIM + col;
#pragma unroll
      for (int r = 0; r < 4; ++r) {
        p[(size_t)r * H_DIM] += acc[mi][ni][r];
      }
    }
  }
}

// ---------------------------------------------------------------------------
// launch: relu+norm -> 3x (pack_w -> gemm(+add) -> norm) ; resid lives in d_out
// ws layout: [0, 32MB): wf16 (reused per layer)  [32MB, 96MB): y16
// ---------------------------------------------------------------------------
extern "C" void kernel_launch(void* const* d_in, const int* in_sizes, int n_in,
                              void* d_out, int out_size, void* d_ws, size_t ws_size,
                              hipStream_t stream) {
  (void)in_sizes; (void)n_in; (void)out_size; (void)ws_size;
  const float* x  = (const float*)d_in[0];
  const float* g0 = (const float*)d_in[1];
  const float* g1 = (const float*)d_in[2];
  const float* g2 = (const float*)d_in[3];
  const float* g3 = (const float*)d_in[4];
  const float* w[3] = {(const float*)d_in[5], (const float*)d_in[6],
                       (const float*)d_in[7]};
  const float* gs[3] = {g1, g2, g3};

  float*     resid = (float*)d_out;  // fp32 resid lives in d_out; final y4 too
  _Float16*  wf16  = (_Float16*)d_ws;
  _Float16*  y16   = (_Float16*)((char*)d_ws + (size_t)H_DIM * H_DIM * 2);

  // z = relu(x); resid = z; y16 = rmsnorm(z)*g0
  rownorm_kernel<0><<<NTOK, 256, 0, stream>>>(x, g0, resid, y16, nullptr);

  for (int l = 0; l < 3; ++l) {
    pack_w_kernel<<<dim3(H_DIM / 8, H_DIM / 256), 256, 0, stream>>>(w[l], wf16);
    gemm128_kernel<<<dim3(H_DIM / 128, NTOK / 128), 256, 0, stream>>>(y16, wf16, resid);
    if (l < 2)
      rownorm_kernel<1><<<NTOK, 256, 0, stream>>>(resid, gs[l], nullptr, y16, nullptr);
    else
      rownorm_kernel<2><<<NTOK, 256, 0, stream>>>(resid, gs[l], nullptr, nullptr, resid);
  }
}